// Round 1
// baseline (1102.655 us; speedup 1.0000x reference)
//
#include <hip/hip_runtime.h>
#include <hip/hip_bf16.h>
#include <math.h>

// Problem constants
#define Hdim 1024
#define Fdim 4096
#define NE   8
#define TOPK 2
#define NT   4096   // B*S = 2*2048 tokens
#define NASSIGN (NT*TOPK)  // 8192

typedef __bf16 bf16x8 __attribute__((ext_vector_type(8)));
typedef __bf16 bf16x4 __attribute__((ext_vector_type(4)));
typedef float  floatx4 __attribute__((ext_vector_type(4)));

// ---------------- async global->LDS (16B per lane, wave-uniform LDS base) ---
__device__ __forceinline__ void ld16_lds(const void* g, void* l) {
  __builtin_amdgcn_global_load_lds(
      (const __attribute__((address_space(1))) void*)g,
      (__attribute__((address_space(3))) void*)l,
      16, 0, 0);
}

// ---------------- x fp32 -> bf16 (flat) ------------------------------------
__global__ void xcvt_kernel(const float* __restrict__ x, __bf16* __restrict__ Xb) {
  int i = blockIdx.x * 256 + threadIdx.x;   // each handles 4 floats
  float4 v = ((const float4*)x)[i];
  bf16x4 o;
  o[0] = (__bf16)v.x; o[1] = (__bf16)v.y; o[2] = (__bf16)v.z; o[3] = (__bf16)v.w;
  ((bf16x4*)Xb)[i] = o;
}

// ---------------- weight transpose+convert: W[E][Kd][Nd] -> Wt[E][Nd][Kd] --
__global__ void transpose_cvt_kernel(const float* __restrict__ W,
                                     __bf16* __restrict__ Wt,
                                     int Kd, int Nd) {
  __shared__ float tile[64][65];
  int e  = blockIdx.z;
  int n0 = blockIdx.x * 64;
  int k0 = blockIdx.y * 64;
  const float* We  = W  + (size_t)e * Kd * Nd;
  __bf16*      Wte = Wt + (size_t)e * Kd * Nd;
  int tx = threadIdx.x & 63, ty = threadIdx.x >> 6;
  #pragma unroll
  for (int r = ty; r < 64; r += 4)
    tile[r][tx] = We[(size_t)(k0 + r) * Nd + n0 + tx];
  __syncthreads();
  #pragma unroll
  for (int r = ty; r < 64; r += 4)
    Wte[(size_t)(n0 + r) * Kd + k0 + tx] = (__bf16)tile[tx][r];
}

// ---------------- gating: logits, softmax, top-2, atomics ------------------
__global__ void gating_kernel(const float* __restrict__ x,
                              const float* __restrict__ wg,
                              int* __restrict__ topk_idx,
                              float* __restrict__ topk_w,
                              int* __restrict__ acnt,
                              int* __restrict__ cnt1,
                              float* __restrict__ probs_sum) {
  int w = threadIdx.x >> 6, l = threadIdx.x & 63;
  int t = blockIdx.x * 4 + w;           // grid = 1024 blocks of 256
  const float* xr = x + (size_t)t * Hdim;
  float acc[NE];
  #pragma unroll
  for (int e = 0; e < NE; ++e) acc[e] = 0.f;
  #pragma unroll
  for (int j = 0; j < Hdim / 64; ++j) {
    int h = j * 64 + l;
    float xv = xr[h];
    const float* wr = wg + h * NE;
    #pragma unroll
    for (int e = 0; e < NE; ++e) acc[e] += xv * wr[e];
  }
  #pragma unroll
  for (int off = 32; off; off >>= 1)
    #pragma unroll
    for (int e = 0; e < NE; ++e) acc[e] += __shfl_xor(acc[e], off, 64);
  if (l == 0) {
    float m = acc[0];
    #pragma unroll
    for (int e = 1; e < NE; ++e) m = fmaxf(m, acc[e]);
    float p[NE], s = 0.f;
    #pragma unroll
    for (int e = 0; e < NE; ++e) { p[e] = expf(acc[e] - m); s += p[e]; }
    float inv = 1.f / s;
    #pragma unroll
    for (int e = 0; e < NE; ++e) p[e] *= inv;
    int e0 = 0; float b0 = p[0];
    #pragma unroll
    for (int e = 1; e < NE; ++e) if (p[e] > b0) { b0 = p[e]; e0 = e; }
    int e1 = (e0 == 0) ? 1 : 0; float b1 = p[e1];
    #pragma unroll
    for (int e = 0; e < NE; ++e)
      if (e != e0 && p[e] > b1) { b1 = p[e]; e1 = e; }
    float s2 = b0 + b1 + 1e-9f;
    topk_idx[t * 2] = e0; topk_idx[t * 2 + 1] = e1;
    topk_w[t * 2] = b0 / s2; topk_w[t * 2 + 1] = b1 / s2;
    atomicAdd(&acnt[e0], 1);
    atomicAdd(&acnt[e1], 1);
    atomicAdd(&cnt1[e0], 1);
    #pragma unroll
    for (int e = 0; e < NE; ++e) atomicAdd(&probs_sum[e], p[e]);
  }
}

// ---------------- offsets + aux loss (single thread, E=8) ------------------
__global__ void offsets_aux_kernel(const int* __restrict__ acnt,
                                   const int* __restrict__ cnt1,
                                   const float* __restrict__ probs_sum,
                                   int* __restrict__ aoff,
                                   int* __restrict__ fill,
                                   float* __restrict__ out_aux) {
  if (threadIdx.x == 0) {
    int o = 0; float aux = 0.f;
    for (int e = 0; e < NE; ++e) {
      aoff[e] = o; fill[e] = o; o += acnt[e];
      aux += ((float)cnt1[e] / (float)NT) * (probs_sum[e] / (float)NT);
    }
    out_aux[0] = (float)NE * aux;
  }
}

// ---------------- scatter token assignments into compact slots -------------
__global__ void scatter_kernel(const int* __restrict__ topk_idx,
                               const float* __restrict__ topk_w,
                               int* __restrict__ fill,
                               int* __restrict__ token_map,
                               float* __restrict__ weight_map) {
  int t = blockIdx.x * 256 + threadIdx.x;
  if (t >= NT) return;
  #pragma unroll
  for (int k = 0; k < TOPK; ++k) {
    int e = topk_idx[t * 2 + k];
    int slot = atomicAdd(&fill[e], 1);
    token_map[slot] = t;
    weight_map[slot] = topk_w[t * 2 + k];
  }
}

// ---------------- MFMA GEMM (m97 structure) --------------------------------
// MODE 0: A = Xb gathered via token_map, KD=1024, ND=4096, epilogue gelu->Hout (bf16)
// MODE 1: A = Hbuf direct,               KD=4096, ND=1024, epilogue atomicAdd->out
template <int KD, int ND, int MODE>
__launch_bounds__(256)
__global__ void moe_gemm_kernel(const __bf16* __restrict__ Abase,
                                const __bf16* __restrict__ Wt,
                                const float* __restrict__ bias,
                                const int* __restrict__ acnt,
                                const int* __restrict__ aoff,
                                const int* __restrict__ token_map,
                                const float* __restrict__ weight_map,
                                __bf16* __restrict__ Hout,
                                float* __restrict__ out) {
  __shared__ __bf16 As[128 * 32];
  __shared__ __bf16 Bs[128 * 32];
  const int e = blockIdx.z;
  const int cnt = acnt[e];
  const int row0 = blockIdx.y * 128;
  if (row0 >= cnt) return;
  const int off = aoff[e];
  const int n0 = blockIdx.x * 128;
  const int tid = threadIdx.x;
  const int w = tid >> 6, l = tid & 63;
  const int arow = tid >> 2;
  const int acol = (tid & 3) * 8;

  // B (weights, already N x K transposed)
  const __bf16* gB0 = Wt + (size_t)e * ((size_t)ND * KD) + (size_t)(n0 + arow) * KD + acol;
  const __bf16* gB1 = gB0 + (size_t)64 * KD;
  // A
  const __bf16* gA0;
  const __bf16* gA1;
  if (MODE == 0) {
    int r0 = off + row0 + arow;
    int r1 = r0 + 64;
    int t0 = token_map[r0 < NASSIGN ? r0 : NASSIGN - 1];
    int t1 = token_map[r1 < NASSIGN ? r1 : NASSIGN - 1];
    gA0 = Abase + (size_t)t0 * KD + acol;
    gA1 = Abase + (size_t)t1 * KD + acol;
  } else {
    gA0 = Abase + (size_t)(off + row0 + arow) * KD + acol;
    gA1 = gA0 + (size_t)64 * KD;
  }

  floatx4 acc[4][4];
  {
    floatx4 z = {0.f, 0.f, 0.f, 0.f};
    #pragma unroll
    for (int i = 0; i < 4; ++i)
      #pragma unroll
      for (int j = 0; j < 4; ++j) acc[i][j] = z;
  }

  __bf16* lA = As + w * 512;   // lane*16B appended by HW; +j*2048 elems for 2nd chunk
  __bf16* lB = Bs + w * 512;
  const int wr = (w >> 1) * 64, wc = (w & 1) * 64;
  const int lrow = l & 15, lq = l >> 4;

  for (int kt = 0; kt < KD; kt += 32) {
    __syncthreads();
    ld16_lds(gA0 + kt, lA);
    ld16_lds(gA1 + kt, lA + 2048);
    ld16_lds(gB0 + kt, lB);
    ld16_lds(gB1 + kt, lB + 2048);
    __syncthreads();   // drains vmcnt -> LDS visible
    bf16x8 af[4], bf[4];
    #pragma unroll
    for (int s = 0; s < 4; ++s) {
      af[s] = *(const bf16x8*)(As + (wr + s * 16 + lrow) * 32 + lq * 8);
      bf[s] = *(const bf16x8*)(Bs + (wc + s * 16 + lrow) * 32 + lq * 8);
    }
    #pragma unroll
    for (int sm = 0; sm < 4; ++sm)
      #pragma unroll
      for (int sn = 0; sn < 4; ++sn)
        acc[sm][sn] = __builtin_amdgcn_mfma_f32_16x16x32_bf16(af[sm], bf[sn], acc[sm][sn], 0, 0, 0);
  }

  // Epilogue. C/D layout: col = lane&15, row = (lane>>4)*4 + reg  [verified m89/m91]
  #pragma unroll
  for (int sm = 0; sm < 4; ++sm) {
    int rowb = row0 + wr + sm * 16 + lq * 4;
    #pragma unroll
    for (int r = 0; r < 4; ++r) {
      int row = rowb + r;
      if (row < cnt) {
        if (MODE == 0) {
          size_t orow = (size_t)(off + row) * ND;
          #pragma unroll
          for (int sn = 0; sn < 4; ++sn) {
            int n = n0 + wc + sn * 16 + lrow;
            float v = acc[sm][sn][r] + bias[e * ND + n];
            v = 0.5f * v * (1.0f + erff(v * 0.70710678118654752f));  // exact gelu
            Hout[orow + n] = (__bf16)v;
          }
        } else {
          int s = off + row;
          int t = token_map[s];
          float wgt = weight_map[s];
          size_t obase = (size_t)t * ND;
          #pragma unroll
          for (int sn = 0; sn < 4; ++sn) {
            int n = n0 + wc + sn * 16 + lrow;
            float v = acc[sm][sn][r] + bias[e * ND + n];
            atomicAdd(&out[obase + n], wgt * v);
          }
        }
      }
    }
  }
}

// ---------------------------------------------------------------------------
extern "C" void kernel_launch(void* const* d_in, const int* in_sizes, int n_in,
                              void* d_out, int out_size, void* d_ws, size_t ws_size,
                              hipStream_t stream) {
  const float* x      = (const float*)d_in[0];
  const float* w_gate = (const float*)d_in[1];
  const float* w_fc   = (const float*)d_in[2];
  const float* b_fc   = (const float*)d_in[3];
  const float* w_proj = (const float*)d_in[4];
  const float* b_proj = (const float*)d_in[5];
  float* out = (float*)d_out;

  char* ws = (char*)d_ws;
  // workspace layout (~211 MB)
  __bf16* Wfct   = (__bf16*)(ws);                          // 8*4096*1024*2 = 64 MB  [E][F][H]
  __bf16* Wprojt = (__bf16*)(ws + 67108864);               // 64 MB                  [E][H][F]
  __bf16* Xb     = (__bf16*)(ws + 134217728);              // 8 MB   T x H bf16
  __bf16* Hbuf   = (__bf16*)(ws + 142606336);              // (8192+128)*4096*2 = 65 MB
  char* tail = ws + 142606336 + (size_t)(NASSIGN + 128) * Fdim * 2;
  int*   token_map  = (int*)tail;
  float* weight_map = (float*)(tail + 32768);
  int*   topk_idx   = (int*)(tail + 65536);
  float* topk_w     = (float*)(tail + 98304);
  int*   cntrs      = (int*)(tail + 131072);
  int*   acnt = cntrs + 0;
  int*   cnt1 = cntrs + 8;
  int*   aoff = cntrs + 16;
  int*   fill = cntrs + 24;
  float* probs_sum = (float*)(cntrs + 32);

  // zero output (atomic accumulation target) and counters
  hipMemsetAsync(d_out, 0, (size_t)out_size * sizeof(float), stream);
  hipMemsetAsync(cntrs, 0, 256, stream);

  // conversions (independent of gating)
  xcvt_kernel<<<(NT * Hdim) / (256 * 4), 256, 0, stream>>>(x, Xb);
  transpose_cvt_kernel<<<dim3(Fdim / 64, Hdim / 64, NE), 256, 0, stream>>>(w_fc, Wfct, Hdim, Fdim);
  transpose_cvt_kernel<<<dim3(Hdim / 64, Fdim / 64, NE), 256, 0, stream>>>(w_proj, Wprojt, Fdim, Hdim);

  // gating -> offsets/aux -> scatter
  gating_kernel<<<NT / 4, 256, 0, stream>>>(x, w_gate, topk_idx, topk_w, acnt, cnt1, probs_sum);
  offsets_aux_kernel<<<1, 64, 0, stream>>>(acnt, cnt1, probs_sum, aoff, fill, out + (size_t)NT * Hdim);
  scatter_kernel<<<NT / 256, 256, 0, stream>>>(topk_idx, topk_w, fill, token_map, weight_map);

  // expert GEMMs
  moe_gemm_kernel<Hdim, Fdim, 0><<<dim3(Fdim / 128, 32, NE), 256, 0, stream>>>(
      Xb, Wfct, b_fc, acnt, aoff, token_map, weight_map, Hbuf, out);
  moe_gemm_kernel<Fdim, Hdim, 1><<<dim3(Hdim / 128, 32, NE), 256, 0, stream>>>(
      Hbuf, Wprojt, b_proj, acnt, aoff, token_map, weight_map, (__bf16*)nullptr, out);

  (void)in_sizes; (void)n_in; (void)ws_size;
}

// Round 2
// 695.545 us; speedup vs baseline: 1.5853x; 1.5853x over previous
//
#include <hip/hip_runtime.h>
#include <hip/hip_bf16.h>
#include <math.h>

// Problem constants
#define Hdim 1024
#define Fdim 4096
#define NE   8
#define TOPK 2
#define NT   4096   // B*S = 2*2048 tokens
#define NASSIGN (NT*TOPK)  // 8192

typedef __bf16 bf16x8 __attribute__((ext_vector_type(8)));
typedef __bf16 bf16x4 __attribute__((ext_vector_type(4)));
typedef float  floatx4 __attribute__((ext_vector_type(4)));

// ---------------- async global->LDS (16B per lane, wave-uniform LDS base) ---
__device__ __forceinline__ void ld16_lds(const void* g, void* l) {
  __builtin_amdgcn_global_load_lds(
      (const __attribute__((address_space(1))) void*)g,
      (__attribute__((address_space(3))) void*)l,
      16, 0, 0);
}

// ---------------- x fp32 -> bf16 (flat) ------------------------------------
__global__ void xcvt_kernel(const float* __restrict__ x, __bf16* __restrict__ Xb) {
  int i = blockIdx.x * 256 + threadIdx.x;   // each handles 4 floats
  float4 v = ((const float4*)x)[i];
  bf16x4 o;
  o[0] = (__bf16)v.x; o[1] = (__bf16)v.y; o[2] = (__bf16)v.z; o[3] = (__bf16)v.w;
  ((bf16x4*)Xb)[i] = o;
}

// ---------------- weight transpose+convert: W[E][Kd][Nd] -> Wt[E][Nd][Kd] --
__global__ void transpose_cvt_kernel(const float* __restrict__ W,
                                     __bf16* __restrict__ Wt,
                                     int Kd, int Nd) {
  __shared__ float tile[64][65];
  int e  = blockIdx.z;
  int n0 = blockIdx.x * 64;
  int k0 = blockIdx.y * 64;
  const float* We  = W  + (size_t)e * Kd * Nd;
  __bf16*      Wte = Wt + (size_t)e * Kd * Nd;
  int tx = threadIdx.x & 63, ty = threadIdx.x >> 6;
  #pragma unroll
  for (int r = ty; r < 64; r += 4)
    tile[r][tx] = We[(size_t)(k0 + r) * Nd + n0 + tx];
  __syncthreads();
  #pragma unroll
  for (int r = ty; r < 64; r += 4)
    Wte[(size_t)(n0 + r) * Kd + k0 + tx] = (__bf16)tile[tx][r];
}

// ---------------- gating: logits, softmax, top-2 (NO atomics) --------------
__global__ void gating_kernel(const float* __restrict__ x,
                              const float* __restrict__ wg,
                              int* __restrict__ topk_idx,
                              float* __restrict__ topk_w,
                              float* __restrict__ probs) {
  int w = threadIdx.x >> 6, l = threadIdx.x & 63;
  int t = blockIdx.x * 4 + w;           // grid = 1024 blocks of 256
  const float* xr = x + (size_t)t * Hdim;
  float acc[NE];
  #pragma unroll
  for (int e = 0; e < NE; ++e) acc[e] = 0.f;
  #pragma unroll
  for (int j = 0; j < Hdim / 64; ++j) {
    int h = j * 64 + l;
    float xv = xr[h];
    const float* wr = wg + h * NE;
    #pragma unroll
    for (int e = 0; e < NE; ++e) acc[e] += xv * wr[e];
  }
  #pragma unroll
  for (int off = 32; off; off >>= 1)
    #pragma unroll
    for (int e = 0; e < NE; ++e) acc[e] += __shfl_xor(acc[e], off, 64);
  if (l == 0) {
    float m = acc[0];
    #pragma unroll
    for (int e = 1; e < NE; ++e) m = fmaxf(m, acc[e]);
    float p[NE], s = 0.f;
    #pragma unroll
    for (int e = 0; e < NE; ++e) { p[e] = expf(acc[e] - m); s += p[e]; }
    float inv = 1.f / s;
    #pragma unroll
    for (int e = 0; e < NE; ++e) p[e] *= inv;
    int e0 = 0; float b0 = p[0];
    #pragma unroll
    for (int e = 1; e < NE; ++e) if (p[e] > b0) { b0 = p[e]; e0 = e; }
    int e1 = (e0 == 0) ? 1 : 0; float b1 = p[e1];
    #pragma unroll
    for (int e = 0; e < NE; ++e)
      if (e != e0 && p[e] > b1) { b1 = p[e]; e1 = e; }
    float s2 = b0 + b1 + 1e-9f;
    topk_idx[t * 2] = e0; topk_idx[t * 2 + 1] = e1;
    topk_w[t * 2] = b0 / s2; topk_w[t * 2 + 1] = b1 / s2;
    #pragma unroll
    for (int e = 0; e < NE; ++e) probs[t * NE + e] = p[e];
  }
}

// ---------------- reduce: counts, offsets, aux loss (1 block) --------------
__global__ void reduce_kernel(const int* __restrict__ topk_idx,
                              const float* __restrict__ probs,
                              int* __restrict__ acnt,
                              int* __restrict__ aoff,
                              int* __restrict__ fill,
                              float* __restrict__ out_aux) {
  __shared__ int s_acnt[NE];
  __shared__ int s_cnt1[NE];
  __shared__ float s_psum[NE];
  int tid = threadIdx.x;
  if (tid < NE) { s_acnt[tid] = 0; s_cnt1[tid] = 0; s_psum[tid] = 0.f; }
  __syncthreads();
  int c_a[NE], c_1[NE];
  float c_p[NE];
  #pragma unroll
  for (int e = 0; e < NE; ++e) { c_a[e] = 0; c_1[e] = 0; c_p[e] = 0.f; }
  for (int t = tid; t < NT; t += 256) {
    int e0 = topk_idx[t * 2], e1 = topk_idx[t * 2 + 1];
    #pragma unroll
    for (int e = 0; e < NE; ++e) {
      c_a[e] += (e == e0) + (e == e1);
      c_1[e] += (e == e0);
      c_p[e] += probs[t * NE + e];
    }
  }
  #pragma unroll
  for (int e = 0; e < NE; ++e) {
    atomicAdd(&s_acnt[e], c_a[e]);
    atomicAdd(&s_cnt1[e], c_1[e]);
    atomicAdd(&s_psum[e], c_p[e]);
  }
  __syncthreads();
  if (tid == 0) {
    int o = 0; float aux = 0.f;
    for (int e = 0; e < NE; ++e) {
      acnt[e] = s_acnt[e];
      aoff[e] = o; fill[e] = o; o += s_acnt[e];
      aux += ((float)s_cnt1[e] / (float)NT) * (s_psum[e] / (float)NT);
    }
    out_aux[0] = (float)NE * aux;
  }
}

// ---------------- scatter with per-block LDS ranking -----------------------
__global__ void scatter_kernel(const int* __restrict__ topk_idx,
                               const float* __restrict__ topk_w,
                               int* __restrict__ fill,
                               int* __restrict__ token_map,
                               float* __restrict__ weight_map) {
  __shared__ int s_cnt[NE];
  __shared__ int s_base[NE];
  int tid = threadIdx.x;
  if (tid < NE) s_cnt[tid] = 0;
  __syncthreads();
  int t = blockIdx.x * 256 + tid;   // 16 blocks x 256 tokens
  int e0 = topk_idx[t * 2], e1 = topk_idx[t * 2 + 1];
  int r0 = atomicAdd(&s_cnt[e0], 1);
  int r1 = atomicAdd(&s_cnt[e1], 1);
  __syncthreads();
  if (tid < NE) s_base[tid] = atomicAdd(&fill[tid], s_cnt[tid]);
  __syncthreads();
  int slot0 = s_base[e0] + r0;
  int slot1 = s_base[e1] + r1;
  token_map[slot0] = t; weight_map[slot0] = topk_w[t * 2];
  token_map[slot1] = t; weight_map[slot1] = topk_w[t * 2 + 1];
}

// ---------------- MFMA GEMM (m97 structure) --------------------------------
// MODE 0: A = Xb gathered via token_map, KD=1024, ND=4096, epilogue gelu->Hout (bf16)
// MODE 1: A = Hbuf direct,               KD=4096, ND=1024, epilogue atomicAdd->out
template <int KD, int ND, int MODE>
__launch_bounds__(256)
__global__ void moe_gemm_kernel(const __bf16* __restrict__ Abase,
                                const __bf16* __restrict__ Wt,
                                const float* __restrict__ bias,
                                const int* __restrict__ acnt,
                                const int* __restrict__ aoff,
                                const int* __restrict__ token_map,
                                const float* __restrict__ weight_map,
                                __bf16* __restrict__ Hout,
                                float* __restrict__ out) {
  __shared__ __bf16 As[128 * 32];
  __shared__ __bf16 Bs[128 * 32];
  const int e = blockIdx.z;
  const int cnt = acnt[e];
  const int row0 = blockIdx.y * 128;
  if (row0 >= cnt) return;
  const int off = aoff[e];
  const int n0 = blockIdx.x * 128;
  const int tid = threadIdx.x;
  const int w = tid >> 6, l = tid & 63;
  const int arow = tid >> 2;
  const int acol = (tid & 3) * 8;

  // B (weights, already N x K transposed)
  const __bf16* gB0 = Wt + (size_t)e * ((size_t)ND * KD) + (size_t)(n0 + arow) * KD + acol;
  const __bf16* gB1 = gB0 + (size_t)64 * KD;
  // A
  const __bf16* gA0;
  const __bf16* gA1;
  if (MODE == 0) {
    int r0 = off + row0 + arow;
    int r1 = r0 + 64;
    int t0 = token_map[r0 < NASSIGN ? r0 : NASSIGN - 1];
    int t1 = token_map[r1 < NASSIGN ? r1 : NASSIGN - 1];
    gA0 = Abase + (size_t)t0 * KD + acol;
    gA1 = Abase + (size_t)t1 * KD + acol;
  } else {
    gA0 = Abase + (size_t)(off + row0 + arow) * KD + acol;
    gA1 = gA0 + (size_t)64 * KD;
  }

  floatx4 acc[4][4];
  {
    floatx4 z = {0.f, 0.f, 0.f, 0.f};
    #pragma unroll
    for (int i = 0; i < 4; ++i)
      #pragma unroll
      for (int j = 0; j < 4; ++j) acc[i][j] = z;
  }

  __bf16* lA = As + w * 512;
  __bf16* lB = Bs + w * 512;
  const int wr = (w >> 1) * 64, wc = (w & 1) * 64;
  const int lrow = l & 15, lq = l >> 4;

  for (int kt = 0; kt < KD; kt += 32) {
    __syncthreads();
    ld16_lds(gA0 + kt, lA);
    ld16_lds(gA1 + kt, lA + 2048);
    ld16_lds(gB0 + kt, lB);
    ld16_lds(gB1 + kt, lB + 2048);
    __syncthreads();   // drains vmcnt -> LDS visible
    bf16x8 af[4], bf[4];
    #pragma unroll
    for (int s = 0; s < 4; ++s) {
      af[s] = *(const bf16x8*)(As + (wr + s * 16 + lrow) * 32 + lq * 8);
      bf[s] = *(const bf16x8*)(Bs + (wc + s * 16 + lrow) * 32 + lq * 8);
    }
    #pragma unroll
    for (int sm = 0; sm < 4; ++sm)
      #pragma unroll
      for (int sn = 0; sn < 4; ++sn)
        acc[sm][sn] = __builtin_amdgcn_mfma_f32_16x16x32_bf16(af[sm], bf[sn], acc[sm][sn], 0, 0, 0);
  }

  // Epilogue. C/D layout: col = lane&15, row = (lane>>4)*4 + reg  [verified m89/m91]
  #pragma unroll
  for (int sm = 0; sm < 4; ++sm) {
    int rowb = row0 + wr + sm * 16 + lq * 4;
    #pragma unroll
    for (int r = 0; r < 4; ++r) {
      int row = rowb + r;
      if (row < cnt) {
        if (MODE == 0) {
          size_t orow = (size_t)(off + row) * ND;
          #pragma unroll
          for (int sn = 0; sn < 4; ++sn) {
            int n = n0 + wc + sn * 16 + lrow;
            float v = acc[sm][sn][r] + bias[e * ND + n];
            v = 0.5f * v * (1.0f + erff(v * 0.70710678118654752f));  // exact gelu
            Hout[orow + n] = (__bf16)v;
          }
        } else {
          int s = off + row;
          int t = token_map[s];
          float wgt = weight_map[s];
          size_t obase = (size_t)t * ND;
          #pragma unroll
          for (int sn = 0; sn < 4; ++sn) {
            int n = n0 + wc + sn * 16 + lrow;
            float v = acc[sm][sn][r] + bias[e * ND + n];
            atomicAdd(&out[obase + n], wgt * v);
          }
        }
      }
    }
  }
}

// ---------------------------------------------------------------------------
extern "C" void kernel_launch(void* const* d_in, const int* in_sizes, int n_in,
                              void* d_out, int out_size, void* d_ws, size_t ws_size,
                              hipStream_t stream) {
  const float* x      = (const float*)d_in[0];
  const float* w_gate = (const float*)d_in[1];
  const float* w_fc   = (const float*)d_in[2];
  const float* b_fc   = (const float*)d_in[3];
  const float* w_proj = (const float*)d_in[4];
  const float* b_proj = (const float*)d_in[5];
  float* out = (float*)d_out;

  char* ws = (char*)d_ws;
  // workspace layout (~211 MB)
  __bf16* Wfct   = (__bf16*)(ws);                          // 64 MB  [E][F][H]
  __bf16* Wprojt = (__bf16*)(ws + 67108864);               // 64 MB  [E][H][F]
  __bf16* Xb     = (__bf16*)(ws + 134217728);              // 8 MB   T x H bf16
  __bf16* Hbuf   = (__bf16*)(ws + 142606336);              // (8192+128)*4096*2 = 65 MB
  char* tail = ws + 142606336 + (size_t)(NASSIGN + 128) * Fdim * 2;
  int*   token_map  = (int*)tail;
  float* weight_map = (float*)(tail + 32768);
  int*   topk_idx   = (int*)(tail + 65536);
  float* topk_w     = (float*)(tail + 98304);
  int*   cntrs      = (int*)(tail + 131072);
  int*   acnt = cntrs + 0;
  int*   aoff = cntrs + 16;
  int*   fill = cntrs + 24;
  float* probs      = (float*)(tail + 131072 + 256);       // 128 KB: NT x NE

  // zero output (atomic accumulation target in MODE 1 GEMM)
  hipMemsetAsync(d_out, 0, (size_t)out_size * sizeof(float), stream);

  // conversions (independent of gating)
  xcvt_kernel<<<(NT * Hdim) / (256 * 4), 256, 0, stream>>>(x, Xb);
  transpose_cvt_kernel<<<dim3(Fdim / 64, Hdim / 64, NE), 256, 0, stream>>>(w_fc, Wfct, Hdim, Fdim);
  transpose_cvt_kernel<<<dim3(Hdim / 64, Fdim / 64, NE), 256, 0, stream>>>(w_proj, Wprojt, Fdim, Hdim);

  // gating -> reduce(offsets/aux) -> scatter
  gating_kernel<<<NT / 4, 256, 0, stream>>>(x, w_gate, topk_idx, topk_w, probs);
  reduce_kernel<<<1, 256, 0, stream>>>(topk_idx, probs, acnt, aoff, fill,
                                       out + (size_t)NT * Hdim);
  scatter_kernel<<<NT / 256, 256, 0, stream>>>(topk_idx, topk_w, fill, token_map, weight_map);

  // expert GEMMs
  moe_gemm_kernel<Hdim, Fdim, 0><<<dim3(Fdim / 128, 32, NE), 256, 0, stream>>>(
      Xb, Wfct, b_fc, acnt, aoff, token_map, weight_map, Hbuf, out);
  moe_gemm_kernel<Fdim, Hdim, 1><<<dim3(Hdim / 128, 32, NE), 256, 0, stream>>>(
      Hbuf, Wprojt, b_proj, acnt, aoff, token_map, weight_map, (__bf16*)nullptr, out);

  (void)in_sizes; (void)n_in; (void)ws_size;
}

// Round 3
// 668.982 us; speedup vs baseline: 1.6483x; 1.0397x over previous
//
#include <hip/hip_runtime.h>
#include <hip/hip_bf16.h>
#include <math.h>

// Problem constants
#define Hdim 1024
#define Fdim 4096
#define NE   8
#define TOPK 2
#define NT   4096   // B*S = 2*2048 tokens
#define NASSIGN (NT*TOPK)  // 8192
#define YROWS (NASSIGN+128)

typedef __bf16 bf16x8 __attribute__((ext_vector_type(8)));
typedef __bf16 bf16x4 __attribute__((ext_vector_type(4)));
typedef float  floatx4 __attribute__((ext_vector_type(4)));

// ---------------- async global->LDS (16B per lane, wave-uniform LDS base) ---
__device__ __forceinline__ void ld16_lds(const void* g, void* l) {
  __builtin_amdgcn_global_load_lds(
      (const __attribute__((address_space(1))) void*)g,
      (__attribute__((address_space(3))) void*)l,
      16, 0, 0);
}

// ---------------- fast exact-ish gelu (tanh form, err ~1e-3) ---------------
__device__ __forceinline__ float gelu_f(float v) {
  float u = 0.7978845608028654f * (v + 0.044715f * v * v * v);
  float ex = __expf(2.0f * u);
  float th = 1.0f - 2.0f / (ex + 1.0f);   // tanh(u), saturates correctly at +-inf
  return 0.5f * v * (1.0f + th);
}

// ---------------- x fp32 -> bf16 (flat) ------------------------------------
__global__ void xcvt_kernel(const float* __restrict__ x, __bf16* __restrict__ Xb) {
  int i = blockIdx.x * 256 + threadIdx.x;   // each handles 4 floats
  float4 v = ((const float4*)x)[i];
  bf16x4 o;
  o[0] = (__bf16)v.x; o[1] = (__bf16)v.y; o[2] = (__bf16)v.z; o[3] = (__bf16)v.w;
  ((bf16x4*)Xb)[i] = o;
}

// ---------------- weight transpose+convert: W[E][Kd][Nd] -> Wt[E][Nd][Kd] --
// phase1: float4 coalesced reads; phase2: bf16x8 (16B/lane) writes
__global__ void transpose_cvt_kernel(const float* __restrict__ W,
                                     __bf16* __restrict__ Wt,
                                     int Kd, int Nd) {
  __shared__ float tile[64][65];
  int e  = blockIdx.z;
  int n0 = blockIdx.x * 64;
  int k0 = blockIdx.y * 64;
  const float* We  = W  + (size_t)e * Kd * Nd;
  __bf16*      Wte = Wt + (size_t)e * Kd * Nd;
  int tid = threadIdx.x;
  int r = tid >> 4, c4 = (tid & 15) * 4;
  #pragma unroll
  for (int p = 0; p < 4; ++p) {
    float4 v = *(const float4*)(We + (size_t)(k0 + p * 16 + r) * Nd + n0 + c4);
    tile[p * 16 + r][c4]     = v.x;
    tile[p * 16 + r][c4 + 1] = v.y;
    tile[p * 16 + r][c4 + 2] = v.z;
    tile[p * 16 + r][c4 + 3] = v.w;
  }
  __syncthreads();
  int n = tid >> 3, k8 = (tid & 7) * 8;
  #pragma unroll
  for (int p = 0; p < 2; ++p) {
    int nn = p * 32 + n;
    bf16x8 o;
    #pragma unroll
    for (int j = 0; j < 8; ++j) o[j] = (__bf16)tile[k8 + j][nn];
    *(bf16x8*)(Wte + (size_t)(n0 + nn) * Kd + k0 + k8) = o;
  }
}

// ---------------- gating: logits, softmax, top-2 (NO atomics) --------------
__global__ void gating_kernel(const float* __restrict__ x,
                              const float* __restrict__ wg,
                              int* __restrict__ topk_idx,
                              float* __restrict__ topk_w,
                              float* __restrict__ probs) {
  int w = threadIdx.x >> 6, l = threadIdx.x & 63;
  int t = blockIdx.x * 4 + w;           // grid = 1024 blocks of 256
  const float* xr = x + (size_t)t * Hdim;
  float acc[NE];
  #pragma unroll
  for (int e = 0; e < NE; ++e) acc[e] = 0.f;
  #pragma unroll
  for (int j = 0; j < Hdim / 64; ++j) {
    int h = j * 64 + l;
    float xv = xr[h];
    const float* wr = wg + h * NE;
    #pragma unroll
    for (int e = 0; e < NE; ++e) acc[e] += xv * wr[e];
  }
  #pragma unroll
  for (int off = 32; off; off >>= 1)
    #pragma unroll
    for (int e = 0; e < NE; ++e) acc[e] += __shfl_xor(acc[e], off, 64);
  if (l == 0) {
    float m = acc[0];
    #pragma unroll
    for (int e = 1; e < NE; ++e) m = fmaxf(m, acc[e]);
    float p[NE], s = 0.f;
    #pragma unroll
    for (int e = 0; e < NE; ++e) { p[e] = expf(acc[e] - m); s += p[e]; }
    float inv = 1.f / s;
    #pragma unroll
    for (int e = 0; e < NE; ++e) p[e] *= inv;
    int e0 = 0; float b0 = p[0];
    #pragma unroll
    for (int e = 1; e < NE; ++e) if (p[e] > b0) { b0 = p[e]; e0 = e; }
    int e1 = (e0 == 0) ? 1 : 0; float b1 = p[e1];
    #pragma unroll
    for (int e = 0; e < NE; ++e)
      if (e != e0 && p[e] > b1) { b1 = p[e]; e1 = e; }
    float s2 = b0 + b1 + 1e-9f;
    topk_idx[t * 2] = e0; topk_idx[t * 2 + 1] = e1;
    topk_w[t * 2] = b0 / s2; topk_w[t * 2 + 1] = b1 / s2;
    #pragma unroll
    for (int e = 0; e < NE; ++e) probs[t * NE + e] = p[e];
  }
}

// ---------------- reduce: counts, offsets, aux loss (1 block) --------------
__global__ void reduce_kernel(const int* __restrict__ topk_idx,
                              const float* __restrict__ probs,
                              int* __restrict__ acnt,
                              int* __restrict__ aoff,
                              int* __restrict__ fill,
                              float* __restrict__ out_aux) {
  __shared__ int s_acnt[NE];
  __shared__ int s_cnt1[NE];
  __shared__ float s_psum[NE];
  int tid = threadIdx.x;
  if (tid < NE) { s_acnt[tid] = 0; s_cnt1[tid] = 0; s_psum[tid] = 0.f; }
  __syncthreads();
  int c_a[NE], c_1[NE];
  float c_p[NE];
  #pragma unroll
  for (int e = 0; e < NE; ++e) { c_a[e] = 0; c_1[e] = 0; c_p[e] = 0.f; }
  for (int t = tid; t < NT; t += 256) {
    int e0 = topk_idx[t * 2], e1 = topk_idx[t * 2 + 1];
    #pragma unroll
    for (int e = 0; e < NE; ++e) {
      c_a[e] += (e == e0) + (e == e1);
      c_1[e] += (e == e0);
      c_p[e] += probs[t * NE + e];
    }
  }
  #pragma unroll
  for (int e = 0; e < NE; ++e) {
    atomicAdd(&s_acnt[e], c_a[e]);
    atomicAdd(&s_cnt1[e], c_1[e]);
    atomicAdd(&s_psum[e], c_p[e]);
  }
  __syncthreads();
  if (tid == 0) {
    int o = 0; float aux = 0.f;
    for (int e = 0; e < NE; ++e) {
      acnt[e] = s_acnt[e];
      aoff[e] = o; fill[e] = o; o += s_acnt[e];
      aux += ((float)s_cnt1[e] / (float)NT) * (s_psum[e] / (float)NT);
    }
    out_aux[0] = (float)NE * aux;
  }
}

// ---------------- scatter with per-block LDS ranking -----------------------
__global__ void scatter_kernel(const int* __restrict__ topk_idx,
                               int* __restrict__ fill,
                               int* __restrict__ token_map,
                               int* __restrict__ islot) {
  __shared__ int s_cnt[NE];
  __shared__ int s_base[NE];
  int tid = threadIdx.x;
  if (tid < NE) s_cnt[tid] = 0;
  __syncthreads();
  int t = blockIdx.x * 256 + tid;   // 16 blocks x 256 tokens
  int e0 = topk_idx[t * 2], e1 = topk_idx[t * 2 + 1];
  int r0 = atomicAdd(&s_cnt[e0], 1);
  int r1 = atomicAdd(&s_cnt[e1], 1);
  __syncthreads();
  if (tid < NE) s_base[tid] = atomicAdd(&fill[tid], s_cnt[tid]);
  __syncthreads();
  int slot0 = s_base[e0] + r0;
  int slot1 = s_base[e1] + r1;
  token_map[slot0] = t;
  token_map[slot1] = t;
  islot[t * 2] = slot0;
  islot[t * 2 + 1] = slot1;
}

// ---------------- MFMA GEMM (m97 structure + XOR-swizzled LDS) -------------
// MODE 0: A = Xb gathered via token_map, KD=1024, ND=4096, epilogue gelu->Hout (bf16)
// MODE 1: A = Hbuf direct, KD=4096 split KPARTS=2, ND=1024, epilogue store fp32 Yout[part]
template <int KD, int ND, int MODE, int KPARTS>
__launch_bounds__(256)
__global__ void moe_gemm_kernel(const __bf16* __restrict__ Abase,
                                const __bf16* __restrict__ Wt,
                                const float* __restrict__ bias,
                                const int* __restrict__ acnt,
                                const int* __restrict__ aoff,
                                const int* __restrict__ token_map,
                                __bf16* __restrict__ Hout,
                                float* __restrict__ Yout) {
  __shared__ __bf16 As[128 * 32];
  __shared__ __bf16 Bs[128 * 32];
  const int e = blockIdx.z;
  const int cnt = acnt[e];
  const int row0 = blockIdx.y * 128;
  if (row0 >= cnt) return;
  const int off = aoff[e];
  const int part  = (KPARTS > 1) ? (int)(blockIdx.x & (KPARTS - 1)) : 0;
  const int n0    = ((KPARTS > 1) ? (int)(blockIdx.x >> 1) : (int)blockIdx.x) * 128;
  const int kbase = part * (KD / KPARTS);
  constexpr int KLEN = KD / KPARTS;
  const int tid = threadIdx.x;
  const int w = tid >> 6, l = tid & 63;
  const int arow = tid >> 2;
  // XOR swizzle: LDS chunk c holds global k-chunk c ^ ((row>>1)&3).
  // Staging lane sits at LDS (row=arow, chunk=tid&3) -> load global chunk (tid&3)^((arow>>1)&3).
  // (pattern period 8 rows; arow and arow+64 share it)
  const int acol = (((tid & 3) ^ ((arow >> 1) & 3)) * 8);

  // B (weights, N x K transposed)
  const __bf16* gB0 = Wt + (size_t)e * ((size_t)ND * KD) + (size_t)(n0 + arow) * KD + kbase + acol;
  const __bf16* gB1 = gB0 + (size_t)64 * KD;
  // A
  const __bf16* gA0;
  const __bf16* gA1;
  if (MODE == 0) {
    int r0 = off + row0 + arow;
    int r1 = r0 + 64;
    int t0 = token_map[r0 < NASSIGN ? r0 : NASSIGN - 1];
    int t1 = token_map[r1 < NASSIGN ? r1 : NASSIGN - 1];
    gA0 = Abase + (size_t)t0 * KD + kbase + acol;
    gA1 = Abase + (size_t)t1 * KD + kbase + acol;
  } else {
    gA0 = Abase + (size_t)(off + row0 + arow) * KD + kbase + acol;
    gA1 = gA0 + (size_t)64 * KD;
  }

  floatx4 acc[4][4];
  {
    floatx4 z = {0.f, 0.f, 0.f, 0.f};
    #pragma unroll
    for (int i = 0; i < 4; ++i)
      #pragma unroll
      for (int j = 0; j < 4; ++j) acc[i][j] = z;
  }

  __bf16* lA = As + w * 512;
  __bf16* lB = Bs + w * 512;
  const int wr = (w >> 1) * 64, wc = (w & 1) * 64;
  const int lrow = l & 15, lq = l >> 4;
  // fragment read: physical chunk = lq ^ ((row>>1)&3); since wr,s*16 are mult of 16,
  // ((row>>1)&3) == ((lrow>>1)&3) -> per-thread constant
  const int ck8 = (lq ^ ((lrow >> 1) & 3)) * 8;

  for (int kt = 0; kt < KLEN; kt += 32) {
    __syncthreads();
    ld16_lds(gA0 + kt, lA);
    ld16_lds(gA1 + kt, lA + 2048);
    ld16_lds(gB0 + kt, lB);
    ld16_lds(gB1 + kt, lB + 2048);
    __syncthreads();   // drains vmcnt -> LDS visible
    bf16x8 af[4], bf[4];
    #pragma unroll
    for (int s = 0; s < 4; ++s) {
      af[s] = *(const bf16x8*)(As + (wr + s * 16 + lrow) * 32 + ck8);
      bf[s] = *(const bf16x8*)(Bs + (wc + s * 16 + lrow) * 32 + ck8);
    }
    #pragma unroll
    for (int sm = 0; sm < 4; ++sm)
      #pragma unroll
      for (int sn = 0; sn < 4; ++sn)
        acc[sm][sn] = __builtin_amdgcn_mfma_f32_16x16x32_bf16(af[sm], bf[sn], acc[sm][sn], 0, 0, 0);
  }

  // Epilogue. C/D layout: col = lane&15, row = (lane>>4)*4 + reg  [verified m89/m91]
  float* yp = (MODE == 1) ? (Yout + (size_t)part * ((size_t)YROWS * ND)) : nullptr;
  #pragma unroll
  for (int sm = 0; sm < 4; ++sm) {
    int rowb = row0 + wr + sm * 16 + lq * 4;
    #pragma unroll
    for (int r = 0; r < 4; ++r) {
      int row = rowb + r;
      if (row < cnt) {
        if (MODE == 0) {
          size_t orow = (size_t)(off + row) * ND;
          #pragma unroll
          for (int sn = 0; sn < 4; ++sn) {
            int n = n0 + wc + sn * 16 + lrow;
            float v = acc[sm][sn][r] + bias[e * ND + n];
            Hout[orow + n] = (__bf16)gelu_f(v);
          }
        } else {
          size_t orow = (size_t)(off + row) * ND;
          #pragma unroll
          for (int sn = 0; sn < 4; ++sn) {
            int n = n0 + wc + sn * 16 + lrow;
            yp[orow + n] = acc[sm][sn][r];
          }
        }
      }
    }
  }
}

// ---------------- combine: out[t] = sum_k w_k (Y0[s_k]+Y1[s_k]+b_proj[e_k]) -
__global__ void combine_kernel(const float* __restrict__ Y,
                               const int* __restrict__ topk_idx,
                               const float* __restrict__ topk_w,
                               const int* __restrict__ islot,
                               const float* __restrict__ b_proj,
                               float* __restrict__ out) {
  int t = blockIdx.x, tid = threadIdx.x;   // 4096 blocks x 256 (4 floats/thread)
  int s0 = islot[t * 2], s1 = islot[t * 2 + 1];
  int e0 = topk_idx[t * 2], e1 = topk_idx[t * 2 + 1];
  float w0 = topk_w[t * 2], w1 = topk_w[t * 2 + 1];
  const float4* Y0 = (const float4*)Y;
  const float4* Y1 = (const float4*)(Y + (size_t)YROWS * Hdim);
  float4 a0 = Y0[(size_t)s0 * 256 + tid];
  float4 a1 = Y1[(size_t)s0 * 256 + tid];
  float4 c0 = Y0[(size_t)s1 * 256 + tid];
  float4 c1 = Y1[(size_t)s1 * 256 + tid];
  float4 b0 = ((const float4*)(b_proj + (size_t)e0 * Hdim))[tid];
  float4 b1 = ((const float4*)(b_proj + (size_t)e1 * Hdim))[tid];
  float4 o;
  o.x = w0 * (a0.x + a1.x + b0.x) + w1 * (c0.x + c1.x + b1.x);
  o.y = w0 * (a0.y + a1.y + b0.y) + w1 * (c0.y + c1.y + b1.y);
  o.z = w0 * (a0.z + a1.z + b0.z) + w1 * (c0.z + c1.z + b1.z);
  o.w = w0 * (a0.w + a1.w + b0.w) + w1 * (c0.w + c1.w + b1.w);
  ((float4*)(out + (size_t)t * Hdim))[tid] = o;
}

// ---------------------------------------------------------------------------
extern "C" void kernel_launch(void* const* d_in, const int* in_sizes, int n_in,
                              void* d_out, int out_size, void* d_ws, size_t ws_size,
                              hipStream_t stream) {
  const float* x      = (const float*)d_in[0];
  const float* w_gate = (const float*)d_in[1];
  const float* w_fc   = (const float*)d_in[2];
  const float* b_fc   = (const float*)d_in[3];
  const float* w_proj = (const float*)d_in[4];
  const float* b_proj = (const float*)d_in[5];
  float* out = (float*)d_out;

  char* ws = (char*)d_ws;
  // workspace layout (~211 MB, same footprint as round-1)
  __bf16* Xb     = (__bf16*)(ws);                    // 8 MB  [T][H] bf16 (dead after GEMM1)
  __bf16* Wfct   = (__bf16*)(ws + 8388608);          // 64 MB [E][F][H]  (dead after GEMM1)
  float*  Ybuf   = (float*)(ws);                     // 68.2 MB, ALIASES Xb+Wfct (written by GEMM2)
  __bf16* Wprojt = (__bf16*)(ws + 75497472);         // 64 MB [E][H][F]
  __bf16* Hbuf   = (__bf16*)(ws + 142606336);        // 68.2 MB (YROWS x F bf16)
  char* tail = ws + 142606336 + (size_t)YROWS * Fdim * 2;   // = ws + 210763776
  int*   token_map  = (int*)tail;                    // 32 KB
  int*   islot      = (int*)(tail + 32768);          // 32 KB
  int*   topk_idx   = (int*)(tail + 65536);
  float* topk_w     = (float*)(tail + 98304);
  int*   cntrs      = (int*)(tail + 131072);
  int*   acnt = cntrs + 0;
  int*   aoff = cntrs + 16;
  int*   fill = cntrs + 24;
  float* probs      = (float*)(tail + 131072 + 256); // 128 KB: NT x NE

  // conversions (gating does not depend on them)
  xcvt_kernel<<<(NT * Hdim) / (256 * 4), 256, 0, stream>>>(x, Xb);
  transpose_cvt_kernel<<<dim3(Fdim / 64, Hdim / 64, NE), 256, 0, stream>>>(w_fc, Wfct, Hdim, Fdim);
  transpose_cvt_kernel<<<dim3(Hdim / 64, Fdim / 64, NE), 256, 0, stream>>>(w_proj, Wprojt, Fdim, Hdim);

  // gating -> reduce(offsets/aux) -> scatter
  gating_kernel<<<NT / 4, 256, 0, stream>>>(x, w_gate, topk_idx, topk_w, probs);
  reduce_kernel<<<1, 256, 0, stream>>>(topk_idx, probs, acnt, aoff, fill,
                                       out + (size_t)NT * Hdim);
  scatter_kernel<<<NT / 256, 256, 0, stream>>>(topk_idx, fill, token_map, islot);

  // expert GEMMs
  moe_gemm_kernel<Hdim, Fdim, 0, 1><<<dim3(Fdim / 128, 32, NE), 256, 0, stream>>>(
      Xb, Wfct, b_fc, acnt, aoff, token_map, Hbuf, nullptr);
  moe_gemm_kernel<Fdim, Hdim, 1, 2><<<dim3((Hdim / 128) * 2, 32, NE), 256, 0, stream>>>(
      Hbuf, Wprojt, nullptr, acnt, aoff, token_map, nullptr, Ybuf);

  // weighted combine + bias
  combine_kernel<<<NT, 256, 0, stream>>>(Ybuf, topk_idx, topk_w, islot, b_proj, out);

  (void)in_sizes; (void)n_in; (void)ws_size;
}

// Round 4
// 645.957 us; speedup vs baseline: 1.7070x; 1.0356x over previous
//
#include <hip/hip_runtime.h>
#include <hip/hip_bf16.h>
#include <math.h>

// Problem constants
#define Hdim 1024
#define Fdim 4096
#define NE   8
#define TOPK 2
#define NT   4096   // B*S = 2*2048 tokens
#define NASSIGN (NT*TOPK)  // 8192
#define YROWS (NASSIGN+128)
#define MAXYT 12    // max row-tiles per expert (cnt <= 1536; expected ~1024 +- 30)

typedef __bf16 bf16x8 __attribute__((ext_vector_type(8)));
typedef __bf16 bf16x4 __attribute__((ext_vector_type(4)));
typedef float  floatx4 __attribute__((ext_vector_type(4)));

// ---------------- async global->LDS (16B per lane, wave-uniform LDS base) ---
__device__ __forceinline__ void ld16_lds(const void* g, void* l) {
  __builtin_amdgcn_global_load_lds(
      (const __attribute__((address_space(1))) void*)g,
      (__attribute__((address_space(3))) void*)l,
      16, 0, 0);
}

// ---------------- fast gelu (tanh form, err ~1e-3) -------------------------
__device__ __forceinline__ float gelu_f(float v) {
  float u = 0.7978845608028654f * (v + 0.044715f * v * v * v);
  float ex = __expf(2.0f * u);
  float th = 1.0f - 2.0f / (ex + 1.0f);   // tanh(u), saturates correctly at +-inf
  return 0.5f * v * (1.0f + th);
}

// ---------------- x fp32 -> bf16 (flat) ------------------------------------
__global__ void xcvt_kernel(const float* __restrict__ x, __bf16* __restrict__ Xb) {
  int i = blockIdx.x * 256 + threadIdx.x;   // each handles 4 floats
  float4 v = ((const float4*)x)[i];
  bf16x4 o;
  o[0] = (__bf16)v.x; o[1] = (__bf16)v.y; o[2] = (__bf16)v.z; o[3] = (__bf16)v.w;
  ((bf16x4*)Xb)[i] = o;
}

// ---------------- weight transpose+convert: W[E][Kd][Nd] -> Wt[E][Nd][Kd] --
__global__ void transpose_cvt_kernel(const float* __restrict__ W,
                                     __bf16* __restrict__ Wt,
                                     int Kd, int Nd) {
  __shared__ float tile[64][65];
  int e  = blockIdx.z;
  int n0 = blockIdx.x * 64;
  int k0 = blockIdx.y * 64;
  const float* We  = W  + (size_t)e * Kd * Nd;
  __bf16*      Wte = Wt + (size_t)e * Kd * Nd;
  int tid = threadIdx.x;
  int r = tid >> 4, c4 = (tid & 15) * 4;
  #pragma unroll
  for (int p = 0; p < 4; ++p) {
    float4 v = *(const float4*)(We + (size_t)(k0 + p * 16 + r) * Nd + n0 + c4);
    tile[p * 16 + r][c4]     = v.x;
    tile[p * 16 + r][c4 + 1] = v.y;
    tile[p * 16 + r][c4 + 2] = v.z;
    tile[p * 16 + r][c4 + 3] = v.w;
  }
  __syncthreads();
  int n = tid >> 3, k8 = (tid & 7) * 8;
  #pragma unroll
  for (int p = 0; p < 2; ++p) {
    int nn = p * 32 + n;
    bf16x8 o;
    #pragma unroll
    for (int j = 0; j < 8; ++j) o[j] = (__bf16)tile[k8 + j][nn];
    *(bf16x8*)(Wte + (size_t)(n0 + nn) * Kd + k0 + k8) = o;
  }
}

// ---------------- gating: logits, softmax, top-2 (NO atomics) --------------
__global__ void gating_kernel(const float* __restrict__ x,
                              const float* __restrict__ wg,
                              int* __restrict__ topk_idx,
                              float* __restrict__ topk_w,
                              float* __restrict__ probs) {
  int w = threadIdx.x >> 6, l = threadIdx.x & 63;
  int t = blockIdx.x * 4 + w;           // grid = 1024 blocks of 256
  const float* xr = x + (size_t)t * Hdim;
  float acc[NE];
  #pragma unroll
  for (int e = 0; e < NE; ++e) acc[e] = 0.f;
  #pragma unroll
  for (int j = 0; j < Hdim / 64; ++j) {
    int h = j * 64 + l;
    float xv = xr[h];
    const float* wr = wg + h * NE;
    #pragma unroll
    for (int e = 0; e < NE; ++e) acc[e] += xv * wr[e];
  }
  #pragma unroll
  for (int off = 32; off; off >>= 1)
    #pragma unroll
    for (int e = 0; e < NE; ++e) acc[e] += __shfl_xor(acc[e], off, 64);
  if (l == 0) {
    float m = acc[0];
    #pragma unroll
    for (int e = 1; e < NE; ++e) m = fmaxf(m, acc[e]);
    float p[NE], s = 0.f;
    #pragma unroll
    for (int e = 0; e < NE; ++e) { p[e] = expf(acc[e] - m); s += p[e]; }
    float inv = 1.f / s;
    #pragma unroll
    for (int e = 0; e < NE; ++e) p[e] *= inv;
    int e0 = 0; float b0 = p[0];
    #pragma unroll
    for (int e = 1; e < NE; ++e) if (p[e] > b0) { b0 = p[e]; e0 = e; }
    int e1 = (e0 == 0) ? 1 : 0; float b1 = p[e1];
    #pragma unroll
    for (int e = 0; e < NE; ++e)
      if (e != e0 && p[e] > b1) { b1 = p[e]; e1 = e; }
    float s2 = b0 + b1 + 1e-9f;
    topk_idx[t * 2] = e0; topk_idx[t * 2 + 1] = e1;
    topk_w[t * 2] = b0 / s2; topk_w[t * 2 + 1] = b1 / s2;
    #pragma unroll
    for (int e = 0; e < NE; ++e) probs[t * NE + e] = p[e];
  }
}

// ---------------- reduce: counts, offsets, aux loss (1 block) --------------
__global__ void reduce_kernel(const int* __restrict__ topk_idx,
                              const float* __restrict__ probs,
                              int* __restrict__ acnt,
                              int* __restrict__ aoff,
                              int* __restrict__ fill,
                              float* __restrict__ out_aux) {
  __shared__ int s_acnt[NE];
  __shared__ int s_cnt1[NE];
  __shared__ float s_psum[NE];
  int tid = threadIdx.x;
  if (tid < NE) { s_acnt[tid] = 0; s_cnt1[tid] = 0; s_psum[tid] = 0.f; }
  __syncthreads();
  int c_a[NE], c_1[NE];
  float c_p[NE];
  #pragma unroll
  for (int e = 0; e < NE; ++e) { c_a[e] = 0; c_1[e] = 0; c_p[e] = 0.f; }
  for (int t = tid; t < NT; t += 256) {
    int e0 = topk_idx[t * 2], e1 = topk_idx[t * 2 + 1];
    #pragma unroll
    for (int e = 0; e < NE; ++e) {
      c_a[e] += (e == e0) + (e == e1);
      c_1[e] += (e == e0);
      c_p[e] += probs[t * NE + e];
    }
  }
  #pragma unroll
  for (int e = 0; e < NE; ++e) {
    atomicAdd(&s_acnt[e], c_a[e]);
    atomicAdd(&s_cnt1[e], c_1[e]);
    atomicAdd(&s_psum[e], c_p[e]);
  }
  __syncthreads();
  if (tid == 0) {
    int o = 0; float aux = 0.f;
    for (int e = 0; e < NE; ++e) {
      acnt[e] = s_acnt[e];
      aoff[e] = o; fill[e] = o; o += s_acnt[e];
      aux += ((float)s_cnt1[e] / (float)NT) * (s_psum[e] / (float)NT);
    }
    out_aux[0] = (float)NE * aux;
  }
}

// ---------------- scatter with per-block LDS ranking -----------------------
__global__ void scatter_kernel(const int* __restrict__ topk_idx,
                               int* __restrict__ fill,
                               int* __restrict__ token_map,
                               int* __restrict__ islot) {
  __shared__ int s_cnt[NE];
  __shared__ int s_base[NE];
  int tid = threadIdx.x;
  if (tid < NE) s_cnt[tid] = 0;
  __syncthreads();
  int t = blockIdx.x * 256 + tid;   // 16 blocks x 256 tokens
  int e0 = topk_idx[t * 2], e1 = topk_idx[t * 2 + 1];
  int r0 = atomicAdd(&s_cnt[e0], 1);
  int r1 = atomicAdd(&s_cnt[e1], 1);
  __syncthreads();
  if (tid < NE) s_base[tid] = atomicAdd(&fill[tid], s_cnt[tid]);
  __syncthreads();
  int slot0 = s_base[e0] + r0;
  int slot1 = s_base[e1] + r1;
  token_map[slot0] = t;
  token_map[slot1] = t;
  islot[t * 2] = slot0;
  islot[t * 2 + 1] = slot1;
}

// ---------------- MFMA GEMM: 3-stage LDS ring, vmcnt-pipelined -------------
// MODE 0: A = Xb gathered via token_map, KD=1024, ND=4096, epilogue gelu->Hout (bf16)
// MODE 1: A = Hbuf direct, KD=4096 split KPARTS=2, ND=1024, epilogue store fp32 Yout[part]
template <int KD, int ND, int MODE, int KPARTS>
__launch_bounds__(256)
__global__ void moe_gemm_kernel(const __bf16* __restrict__ Abase,
                                const __bf16* __restrict__ Wt,
                                const float* __restrict__ bias,
                                const int* __restrict__ acnt,
                                const int* __restrict__ aoff,
                                const int* __restrict__ token_map,
                                __bf16* __restrict__ Hout,
                                float* __restrict__ Yout) {
  __shared__ __bf16 As[3 * 4096];   // 3 stages x 8KB
  __shared__ __bf16 Bs[3 * 4096];
  const int e = blockIdx.z;
  const int cnt = acnt[e];
  const int row0 = blockIdx.y * 128;
  if (row0 >= cnt) return;
  const int off = aoff[e];
  const int part  = (KPARTS > 1) ? (int)(blockIdx.x & (KPARTS - 1)) : 0;
  const int n0    = ((KPARTS > 1) ? (int)(blockIdx.x >> 1) : (int)blockIdx.x) * 128;
  const int kbase = part * (KD / KPARTS);
  constexpr int KLEN = KD / KPARTS;
  constexpr int NIT  = KLEN / 32;
  const int tid = threadIdx.x;
  const int w = tid >> 6, l = tid & 63;
  const int arow = tid >> 2;
  // XOR swizzle: LDS chunk c holds global k-chunk c ^ ((row>>1)&3).
  const int acol = (((tid & 3) ^ ((arow >> 1) & 3)) * 8);

  const __bf16* gB0 = Wt + (size_t)e * ((size_t)ND * KD) + (size_t)(n0 + arow) * KD + kbase + acol;
  const __bf16* gB1 = gB0 + (size_t)64 * KD;
  const __bf16* gA0;
  const __bf16* gA1;
  if (MODE == 0) {
    int r0 = off + row0 + arow;
    int r1 = r0 + 64;
    int t0 = token_map[r0 < NASSIGN ? r0 : NASSIGN - 1];
    int t1 = token_map[r1 < NASSIGN ? r1 : NASSIGN - 1];
    gA0 = Abase + (size_t)t0 * KD + kbase + acol;
    gA1 = Abase + (size_t)t1 * KD + kbase + acol;
  } else {
    gA0 = Abase + (size_t)(off + row0 + arow) * KD + kbase + acol;
    gA1 = gA0 + (size_t)64 * KD;
  }

  floatx4 acc[4][4];
  {
    floatx4 z = {0.f, 0.f, 0.f, 0.f};
    #pragma unroll
    for (int i = 0; i < 4; ++i)
      #pragma unroll
      for (int j = 0; j < 4; ++j) acc[i][j] = z;
  }

  const int wr = (w >> 1) * 64, wc = (w & 1) * 64;
  const int lrow = l & 15, lq = l >> 4;
  const int ck8 = (lq ^ ((lrow >> 1) & 3)) * 8;   // swizzled fragment chunk

  const int woff = w * 512;   // per-wave staging base within a stage

  // issue loads for stage s covering k-chunk kt (per wave: 4 x 16B x 64 lanes)
  #define ISSUE_STAGE(s, kt)                                  \
    do {                                                      \
      __bf16* a_ = As + (s) * 4096 + woff;                    \
      __bf16* b_ = Bs + (s) * 4096 + woff;                    \
      ld16_lds(gA0 + (kt), a_);                               \
      ld16_lds(gA1 + (kt), a_ + 2048);                        \
      ld16_lds(gB0 + (kt), b_);                               \
      ld16_lds(gB1 + (kt), b_ + 2048);                        \
    } while (0)

  // prologue: 2 stages in flight
  ISSUE_STAGE(0, 0);
  ISSUE_STAGE(1, 32);

  int st = 0, s_next = 2;
  for (int it = 0; it < NIT; ++it) {
    // wait for THIS wave's stage-it loads (leave next stage's 4 in flight),
    // then barrier: all waves' stage-it loads complete -> LDS stage st valid.
    __asm__ volatile("" ::: "memory");
    if (it + 1 < NIT) __builtin_amdgcn_s_waitcnt(0xF74);   // vmcnt(4)
    else              __builtin_amdgcn_s_waitcnt(0xF70);   // vmcnt(0)
    __builtin_amdgcn_s_barrier();
    __asm__ volatile("" ::: "memory");
    // All waves done computing stage (it-1) == buffer s_next -> safe to refill.
    if (it + 2 < NIT) ISSUE_STAGE(s_next, (it + 2) * 32);

    const __bf16* Ab = As + st * 4096;
    const __bf16* Bb = Bs + st * 4096;
    bf16x8 af[4], bf[4];
    #pragma unroll
    for (int s = 0; s < 4; ++s) {
      af[s] = *(const bf16x8*)(Ab + (wr + s * 16 + lrow) * 32 + ck8);
      bf[s] = *(const bf16x8*)(Bb + (wc + s * 16 + lrow) * 32 + ck8);
    }
    #pragma unroll
    for (int sm = 0; sm < 4; ++sm)
      #pragma unroll
      for (int sn = 0; sn < 4; ++sn)
        acc[sm][sn] = __builtin_amdgcn_mfma_f32_16x16x32_bf16(af[sm], bf[sn], acc[sm][sn], 0, 0, 0);

    st = (st == 2) ? 0 : st + 1;
    s_next = (s_next == 2) ? 0 : s_next + 1;
  }
  #undef ISSUE_STAGE

  // Epilogue. C/D layout: col = lane&15, row = (lane>>4)*4 + reg  [verified m89/m91]
  float* yp = (MODE == 1) ? (Yout + (size_t)part * ((size_t)YROWS * ND)) : nullptr;
  #pragma unroll
  for (int sm = 0; sm < 4; ++sm) {
    int rowb = row0 + wr + sm * 16 + lq * 4;
    #pragma unroll
    for (int r = 0; r < 4; ++r) {
      int row = rowb + r;
      if (row < cnt) {
        if (MODE == 0) {
          size_t orow = (size_t)(off + row) * ND;
          #pragma unroll
          for (int sn = 0; sn < 4; ++sn) {
            int n = n0 + wc + sn * 16 + lrow;
            float v = acc[sm][sn][r] + bias[e * ND + n];
            Hout[orow + n] = (__bf16)gelu_f(v);
          }
        } else {
          size_t orow = (size_t)(off + row) * ND;
          #pragma unroll
          for (int sn = 0; sn < 4; ++sn) {
            int n = n0 + wc + sn * 16 + lrow;
            yp[orow + n] = acc[sm][sn][r];
          }
        }
      }
    }
  }
}

// ---------------- combine: out[t] = sum_k w_k (Y0[s_k]+Y1[s_k]+b_proj[e_k]) -
__global__ void combine_kernel(const float* __restrict__ Y,
                               const int* __restrict__ topk_idx,
                               const float* __restrict__ topk_w,
                               const int* __restrict__ islot,
                               const float* __restrict__ b_proj,
                               float* __restrict__ out) {
  int t = blockIdx.x, tid = threadIdx.x;   // 4096 blocks x 256 (4 floats/thread)
  int s0 = islot[t * 2], s1 = islot[t * 2 + 1];
  int e0 = topk_idx[t * 2], e1 = topk_idx[t * 2 + 1];
  float w0 = topk_w[t * 2], w1 = topk_w[t * 2 + 1];
  const float4* Y0 = (const float4*)Y;
  const float4* Y1 = (const float4*)(Y + (size_t)YROWS * Hdim);
  float4 a0 = Y0[(size_t)s0 * 256 + tid];
  float4 a1 = Y1[(size_t)s0 * 256 + tid];
  float4 c0 = Y0[(size_t)s1 * 256 + tid];
  float4 c1 = Y1[(size_t)s1 * 256 + tid];
  float4 b0 = ((const float4*)(b_proj + (size_t)e0 * Hdim))[tid];
  float4 b1 = ((const float4*)(b_proj + (size_t)e1 * Hdim))[tid];
  float4 o;
  o.x = w0 * (a0.x + a1.x + b0.x) + w1 * (c0.x + c1.x + b1.x);
  o.y = w0 * (a0.y + a1.y + b0.y) + w1 * (c0.y + c1.y + b1.y);
  o.z = w0 * (a0.z + a1.z + b0.z) + w1 * (c0.z + c1.z + b1.z);
  o.w = w0 * (a0.w + a1.w + b0.w) + w1 * (c0.w + c1.w + b1.w);
  ((float4*)(out + (size_t)t * Hdim))[tid] = o;
}

// ---------------------------------------------------------------------------
extern "C" void kernel_launch(void* const* d_in, const int* in_sizes, int n_in,
                              void* d_out, int out_size, void* d_ws, size_t ws_size,
                              hipStream_t stream) {
  const float* x      = (const float*)d_in[0];
  const float* w_gate = (const float*)d_in[1];
  const float* w_fc   = (const float*)d_in[2];
  const float* b_fc   = (const float*)d_in[3];
  const float* w_proj = (const float*)d_in[4];
  const float* b_proj = (const float*)d_in[5];
  float* out = (float*)d_out;

  char* ws = (char*)d_ws;
  // workspace layout (~211 MB)
  __bf16* Xb     = (__bf16*)(ws);                    // 8 MB  [T][H] bf16 (dead after GEMM1)
  __bf16* Wfct   = (__bf16*)(ws + 8388608);          // 64 MB [E][F][H]  (dead after GEMM1)
  float*  Ybuf   = (float*)(ws);                     // 68.2 MB, ALIASES Xb+Wfct (written by GEMM2)
  __bf16* Wprojt = (__bf16*)(ws + 75497472);         // 64 MB [E][H][F]
  __bf16* Hbuf   = (__bf16*)(ws + 142606336);        // 68.2 MB (YROWS x F bf16)
  char* tail = ws + 142606336 + (size_t)YROWS * Fdim * 2;   // = ws + 210763776
  int*   token_map  = (int*)tail;                    // 32 KB
  int*   islot      = (int*)(tail + 32768);          // 32 KB
  int*   topk_idx   = (int*)(tail + 65536);
  float* topk_w     = (float*)(tail + 98304);
  int*   cntrs      = (int*)(tail + 131072);
  int*   acnt = cntrs + 0;
  int*   aoff = cntrs + 16;
  int*   fill = cntrs + 24;
  float* probs      = (float*)(tail + 131072 + 256); // 128 KB: NT x NE

  // conversions (gating does not depend on them)
  xcvt_kernel<<<(NT * Hdim) / (256 * 4), 256, 0, stream>>>(x, Xb);
  transpose_cvt_kernel<<<dim3(Fdim / 64, Hdim / 64, NE), 256, 0, stream>>>(w_fc, Wfct, Hdim, Fdim);
  transpose_cvt_kernel<<<dim3(Hdim / 64, Fdim / 64, NE), 256, 0, stream>>>(w_proj, Wprojt, Fdim, Hdim);

  // gating -> reduce(offsets/aux) -> scatter
  gating_kernel<<<NT / 4, 256, 0, stream>>>(x, w_gate, topk_idx, topk_w, probs);
  reduce_kernel<<<1, 256, 0, stream>>>(topk_idx, probs, acnt, aoff, fill,
                                       out + (size_t)NT * Hdim);
  scatter_kernel<<<NT / 256, 256, 0, stream>>>(topk_idx, fill, token_map, islot);

  // expert GEMMs (y-grid compacted: cnt/expert ~1024, 12 tiles = headroom to 1536)
  moe_gemm_kernel<Hdim, Fdim, 0, 1><<<dim3(Fdim / 128, MAXYT, NE), 256, 0, stream>>>(
      Xb, Wfct, b_fc, acnt, aoff, token_map, Hbuf, nullptr);
  moe_gemm_kernel<Fdim, Hdim, 1, 2><<<dim3((Hdim / 128) * 2, MAXYT, NE), 256, 0, stream>>>(
      Hbuf, Wprojt, nullptr, acnt, aoff, token_map, nullptr, Ybuf);

  // weighted combine + bias
  combine_kernel<<<NT, 256, 0, stream>>>(Ybuf, topk_idx, topk_w, islot, b_proj, out);

  (void)in_sizes; (void)n_in; (void)ws_size;
}